// Round 4
// baseline (405.463 us; speedup 1.0000x reference)
//
#include <hip/hip_runtime.h>

#define D_CH 32
#define L_LEN 65536
#define W_TAPS 5
#define VEC 16
#define TPB 256
// tiles per (b,g) row: L / (TPB*VEC) = 65536 / 4096 = 16
#define TILES 16

typedef float float4v __attribute__((ext_vector_type(4)));

__global__ __launch_bounds__(TPB) void grouped_conv1d_kernel(
    const float* __restrict__ x,   // (32, 32, L) fp32
    const float* __restrict__ k0,  // (4, 8, 5) fp32
    const float* __restrict__ k1,
    const float* __restrict__ k2,
    const float* __restrict__ k3,
    float* __restrict__ out)       // (32, 16, L) fp32
{
    const int bid  = blockIdx.x;
    const int tile = bid & (TILES - 1);
    const int g    = (bid >> 4) & 3;
    const int b    = bid >> 6;
    const int l0   = tile * (TPB * VEC) + (int)threadIdx.x * VEC;

    const float* kp = (g == 0) ? k0 : (g == 1) ? k1 : (g == 2) ? k2 : k3;

    float acc[4][VEC];
#pragma unroll
    for (int o = 0; o < 4; ++o)
#pragma unroll
        for (int i = 0; i < VEC; ++i) acc[o][i] = 0.f;

    const float* xb = x + ((size_t)b * D_CH + (size_t)g * 8) * L_LEN;

#pragma unroll
    for (int c = 0; c < 8; ++c) {
        const float* xc = xb + (size_t)c * L_LEN;

        // need x[l0-2 .. l0+17] : 20 values. Main 16 via four aligned 16B loads.
        float vf[VEC + 4];
        vf[0] = (l0 >= 2) ? xc[l0 - 2] : 0.f;
        vf[1] = (l0 >= 1) ? xc[l0 - 1] : 0.f;
#pragma unroll
        for (int q = 0; q < 4; ++q) {
            float4v m = *(const float4v*)(xc + l0 + 4 * q);
#pragma unroll
            for (int i = 0; i < 4; ++i) vf[2 + 4 * q + i] = m[i];
        }
        vf[18] = (l0 + 16 < L_LEN) ? xc[l0 + 16] : 0.f;
        vf[19] = (l0 + 17 < L_LEN) ? xc[l0 + 17] : 0.f;

        // taps for this input channel: ker[o][c][w], wave-uniform
        float kf[4][W_TAPS];
#pragma unroll
        for (int o = 0; o < 4; ++o)
#pragma unroll
            for (int w = 0; w < W_TAPS; ++w)
                kf[o][w] = kp[(o * 8 + c) * W_TAPS + w];

#pragma unroll
        for (int o = 0; o < 4; ++o)
#pragma unroll
            for (int w = 0; w < W_TAPS; ++w) {
                const float kk = kf[o][w];
#pragma unroll
                for (int i = 0; i < VEC; ++i)
                    acc[o][i] += vf[i + w] * kk;
            }
    }

#pragma unroll
    for (int o = 0; o < 4; ++o) {
        float* op = out + (((size_t)b * 16 + (size_t)(g * 4 + o)) * L_LEN) + l0;
#pragma unroll
        for (int q = 0; q < 4; ++q) {
            float4v s;
#pragma unroll
            for (int i = 0; i < 4; ++i) s[i] = acc[o][4 * q + i];
            *(float4v*)(op + 4 * q) = s;
        }
    }
}

extern "C" void kernel_launch(void* const* d_in, const int* in_sizes, int n_in,
                              void* d_out, int out_size, void* d_ws, size_t ws_size,
                              hipStream_t stream) {
    const float* x  = (const float*)d_in[0];
    const float* k0 = (const float*)d_in[1];
    const float* k1 = (const float*)d_in[2];
    const float* k2 = (const float*)d_in[3];
    const float* k3 = (const float*)d_in[4];
    float* out = (float*)d_out;

    const int blocks = 32 * 4 * TILES;  // 2048
    grouped_conv1d_kernel<<<blocks, TPB, 0, stream>>>(x, k0, k1, k2, k3, out);
}